// Round 9
// baseline (913.778 us; speedup 1.0000x reference)
//
#include <hip/hip_runtime.h>
#include <cstdint>

#define NB 2
#define NN 1024
#define MM 2048
#define DD 512
#define HH 64
#define ST 68          // padded LDS stride (floats)
#define STB 72         // padded LDS stride (ushorts)
#define GRID 512

typedef __attribute__((ext_vector_type(8))) short bf16x8;
typedef __attribute__((ext_vector_type(4))) float f32x4;

__device__ inline ushort f2bf(float x) {
  union { float f; uint32_t u; } v; v.f = x;
  uint32_t u = v.u;
  u += 0x7FFF + ((u >> 16) & 1);      // RNE
  return (ushort)(u >> 16);
}
__device__ inline float bflo(uint32_t d) { return __uint_as_float(d << 16); }
__device__ inline float bfhi(uint32_t d) { return __uint_as_float(d & 0xFFFF0000u); }

#define GLDS(gp, lp) \
  __builtin_amdgcn_global_load_lds( \
      (const __attribute__((address_space(1))) void*)(gp), \
      (__attribute__((address_space(3))) void*)(lp), 16, 0, 0)

struct KP {
  const float *update, *mask, *cand;
  const int *span_begin, *prune, *span_len;
  const float *Wl, *Wr, *b_h, *dist_emb, *v_out, *Wg, *b_gate;
  float *out;
  int *bar;                      // [cnt, gen] zeroed by hipMemsetAsync each call
  float *left; ushort *right_bf; ushort *probs_bf; ushort *ctxt_bf;
  float *upd1, *upd2; ushort *Ubf0, *Ubf1, *UT, *WgT;
};

// ---- software grid barrier (all GRID blocks resident by capacity arithmetic:
// launch_bounds(256,2) => 2 blocks/CU by VGPR; LDS 2x39.3KB <= 160KB/CU) ----
__device__ inline void gsync(int* bar) {
  __syncthreads();
  __threadfence();                          // release: flush this block's writes
  if (threadIdx.x == 0) {
    int* cnt = bar;
    int* gen = bar + 1;
    const int g = atomicAdd(gen, 0);
    if (atomicAdd(cnt, 1) == GRID - 1) {
      atomicExch(cnt, 0);
      __threadfence();
      atomicAdd(gen, 1);
    } else {
      while (atomicAdd(gen, 0) == g) __builtin_amdgcn_s_sleep(2);
    }
    __threadfence();                        // acquire: inv stale L1/L2 lines
  }
  __syncthreads();
}

// ---- conv tile: fp32 [R][C] tile -> optional bf16 row-major + bf16 T [C][R] ----
__device__ void conv_tile(const float* __restrict__ in, ushort* out_row,
                          ushort* __restrict__ out_T, int R, int C,
                          int r0, int c0, char* smem) {
  float (*tile)[65] = (float(*)[65])smem;   // 16.6 KB
  const int tx = threadIdx.x & 15, ty = threadIdx.x >> 4;
#pragma unroll
  for (int p = 0; p < 4; ++p) {
    const int r = ty + p * 16;
    const float4 v = *(const float4*)&in[(size_t)(r0 + r) * C + c0 + tx * 4];
    tile[r][tx * 4 + 0] = v.x; tile[r][tx * 4 + 1] = v.y;
    tile[r][tx * 4 + 2] = v.z; tile[r][tx * 4 + 3] = v.w;
    if (out_row) {
      ushort4 o = make_ushort4(f2bf(v.x), f2bf(v.y), f2bf(v.z), f2bf(v.w));
      *(ushort4*)&out_row[(size_t)(r0 + r) * C + c0 + tx * 4] = o;
    }
  }
  __syncthreads();
#pragma unroll
  for (int p = 0; p < 4; ++p) {
    const int rr = ty + p * 16;
    ushort4 o;
    o.x = f2bf(tile[tx * 4 + 0][rr]);
    o.y = f2bf(tile[tx * 4 + 1][rr]);
    o.z = f2bf(tile[tx * 4 + 2][rr]);
    o.w = f2bf(tile[tx * 4 + 3][rr]);
    *(ushort4*)&out_T[(size_t)(c0 + rr) * R + r0 + tx * 4] = o;
  }
  __syncthreads();                          // LDS reused by next tile / phase
}

// ---- lr: left(f32)=U@Wl, right(bf16)=U@Wr for 4 rows (vb in [0,512)) ----
__device__ void lr_phase(const KP& P, const float* __restrict__ U, int vb,
                         char* smem) {
  float (*u)[DD] = (float(*)[DD])smem;      // 4 rows, 8 KB
  const int tid = threadIdx.x;
  const float4* Uv = (const float4*)(U + (size_t)vb * 4 * DD);
  float4* uv = (float4*)&u[0][0];
#pragma unroll
  for (int t = 0; t < 2; ++t) uv[tid + t * 256] = Uv[tid + t * 256];
  __syncthreads();
  const int h = tid & 63;
  const int isR = (tid >> 6) & 1;
  const int rsel = tid >> 7;                // rows rsel, rsel+2
  const float* __restrict__ W = isR ? P.Wr : P.Wl;
  float acc[2] = {0.f, 0.f};
  for (int k0 = 0; k0 < DD; k0 += 4) {
    float w0 = W[(k0 + 0) * HH + h];
    float w1 = W[(k0 + 1) * HH + h];
    float w2 = W[(k0 + 2) * HH + h];
    float w3 = W[(k0 + 3) * HH + h];
#pragma unroll
    for (int r = 0; r < 2; ++r) {
      float4 u4 = *(const float4*)&u[rsel + r * 2][k0];
      acc[r] = fmaf(u4.w, w3, fmaf(u4.z, w2, fmaf(u4.y, w1, fmaf(u4.x, w0, acc[r]))));
    }
  }
  if (isR) {
#pragma unroll
    for (int r = 0; r < 2; ++r)
      P.right_bf[(size_t)(vb * 4 + rsel + r * 2) * HH + h] = f2bf(acc[r]);
  } else {
#pragma unroll
    for (int r = 0; r < 2; ++r)
      P.left[(size_t)(vb * 4 + rsel + r * 2) * HH + h] = acc[r];
  }
  __syncthreads();
}

// ---- fused score + softmax -> bf16 probs; vb in [0,512): b=vb>>8, 4 rows ----
__device__ void score_phase(const KP& P, int vb, char* smem) {
  ushort (*Rt)[STB] = (ushort(*)[STB])(smem);                  // 9216
  ushort (*LDb)[10][STB] = (ushort(*)[10][STB])(smem + 9216);  // 5760
  float (*Dbh)[ST] = (float(*)[ST])(smem + 14976);             // 2720
  float (*Lt)[ST] = (float(*)[ST])(smem + 17696);              // 1088
  float (*Sc)[NN] = (float(*)[NN])(smem + 18784);              // 16384
  int* sbj = (int*)(smem + 35168);                             // 4096
  const int b = vb >> 8;
  const int r0 = (vb & 255) * 4;
  const int tid = threadIdx.x;
  const int wave = tid >> 6, lane = tid & 63;
  const int row = r0 + wave;

  for (int f = tid; f < 160; f += 256) {
    int bk = f >> 4, h4 = f & 15;
    float4 d = *(const float4*)&P.dist_emb[bk * HH + h4 * 4];
    float4 bh = *(const float4*)&P.b_h[h4 * 4];
    d.x += bh.x; d.y += bh.y; d.z += bh.z; d.w += bh.w;
    *(float4*)&Dbh[bk][h4 * 4] = d;
  }
  if (tid < 64) {
    int r = tid >> 4, h4 = tid & 15;
    *(float4*)&Lt[r][h4 * 4] =
        *(const float4*)&P.left[((size_t)b * NN + r0 + r) * HH + h4 * 4];
  }
  for (int t = tid; t < NN; t += 256) sbj[t] = P.span_begin[b * NN + t];
  __syncthreads();
  for (int f = tid; f < 2560; f += 256) {
    int i = f / 640;
    int rem = f - i * 640;
    int bk = rem >> 6, h = rem & 63;
    LDb[i][bk][h] = f2bf(Lt[i][h] + Dbh[bk][h]);
  }
  float4 vr[16];
#pragma unroll
  for (int hq = 0; hq < 16; ++hq) vr[hq] = *(const float4*)&P.v_out[hq * 4];
  const int my_sbi = P.span_begin[(size_t)b * NN + row];
  const float* maskrow = P.mask + ((size_t)b * NN + row) * NN;

#pragma unroll 1
  for (int c = 0; c < 16; ++c) {
    __syncthreads();                   // Rt reuse boundary (covers LDb fill at c=0)
#pragma unroll
    for (int t = 0; t < 2; ++t) {
      const int f = tid + t * 256;
      const int r = f >> 3, u8 = f & 7;
      *(bf16x8*)&Rt[r][u8 * 8] =
          *(const bf16x8*)&P.right_bf[((size_t)b * NN + c * 64 + r) * HH + u8 * 8];
    }
    __syncthreads();
    int d = sbj[c * 64 + lane] - my_sbi;
    d = d < 0 ? -d : d;
    const int bk =
        d <= 4 ? d : (d <= 7 ? 5 : (d <= 15 ? 6 : (d <= 31 ? 7 : (d <= 63 ? 8 : 9))));
    const ushort* zp = &LDb[wave][bk][0];
    const ushort* rp = &Rt[lane][0];
    float acc0 = 0.f, acc1 = 0.f;      // two chains: break serial fmaf dependency
#pragma unroll
    for (int oct = 0; oct < 8; oct += 2) {
      {
        const uint4 zd = *(const uint4*)&zp[oct * 8];
        const uint4 rd = *(const uint4*)&rp[oct * 8];
        const float4 v0 = vr[2 * oct], v1 = vr[2 * oct + 1];
        acc0 = fmaf(fmaxf(bflo(zd.x) + bflo(rd.x), 0.f), v0.x, acc0);
        acc0 = fmaf(fmaxf(bfhi(zd.x) + bfhi(rd.x), 0.f), v0.y, acc0);
        acc0 = fmaf(fmaxf(bflo(zd.y) + bflo(rd.y), 0.f), v0.z, acc0);
        acc0 = fmaf(fmaxf(bfhi(zd.y) + bfhi(rd.y), 0.f), v0.w, acc0);
        acc0 = fmaf(fmaxf(bflo(zd.z) + bflo(rd.z), 0.f), v1.x, acc0);
        acc0 = fmaf(fmaxf(bfhi(zd.z) + bfhi(rd.z), 0.f), v1.y, acc0);
        acc0 = fmaf(fmaxf(bflo(zd.w) + bflo(rd.w), 0.f), v1.z, acc0);
        acc0 = fmaf(fmaxf(bfhi(zd.w) + bfhi(rd.w), 0.f), v1.w, acc0);
      }
      {
        const uint4 zd = *(const uint4*)&zp[(oct + 1) * 8];
        const uint4 rd = *(const uint4*)&rp[(oct + 1) * 8];
        const float4 v0 = vr[2 * oct + 2], v1 = vr[2 * oct + 3];
        acc1 = fmaf(fmaxf(bflo(zd.x) + bflo(rd.x), 0.f), v0.x, acc1);
        acc1 = fmaf(fmaxf(bfhi(zd.x) + bfhi(rd.x), 0.f), v0.y, acc1);
        acc1 = fmaf(fmaxf(bflo(zd.y) + bflo(rd.y), 0.f), v0.z, acc1);
        acc1 = fmaf(fmaxf(bfhi(zd.y) + bfhi(rd.y), 0.f), v0.w, acc1);
        acc1 = fmaf(fmaxf(bflo(zd.z) + bflo(rd.z), 0.f), v1.x, acc1);
        acc1 = fmaf(fmaxf(bfhi(zd.z) + bfhi(rd.z), 0.f), v1.y, acc1);
        acc1 = fmaf(fmaxf(bflo(zd.w) + bflo(rd.w), 0.f), v1.z, acc1);
        acc1 = fmaf(fmaxf(bfhi(zd.w) + bfhi(rd.w), 0.f), v1.w, acc1);
      }
    }
    const float mval = maskrow[c * 64 + lane];
    Sc[wave][c * 64 + lane] = (acc0 + acc1) - (1.0f - mval) * 1e23f;
  }
  float mx = -3.0e38f;
#pragma unroll
  for (int c = 0; c < 16; ++c) mx = fmaxf(mx, Sc[wave][c * 64 + lane]);
#pragma unroll
  for (int off = 32; off; off >>= 1) mx = fmaxf(mx, __shfl_xor(mx, off));
  float sum = 0.f;
#pragma unroll
  for (int c = 0; c < 16; ++c) {
    const float e = __expf(Sc[wave][c * 64 + lane] - mx);
    Sc[wave][c * 64 + lane] = e;
    sum += e;
  }
#pragma unroll
  for (int off = 32; off; off >>= 1) sum += __shfl_xor(sum, off);
  const float inv = 1.0f / sum;
  ushort* prow = P.probs_bf + ((size_t)b * NN + row) * NN;
#pragma unroll
  for (int c = 0; c < 16; ++c)
    prow[c * 64 + lane] = f2bf(Sc[wave][c * 64 + lane] * inv);
  __syncthreads();
}

// ---- ctxt(bf16) = P @ U via bf16 MFMA; vb in [0,256) ----
__device__ void ctxt_phase(const KP& P, int vb, char* smem) {
  ushort* As = (ushort*)smem;
  ushort* Bs = (ushort*)(smem + 8192);
  const int b = vb >> 7;
  const int rem = vb & 127;
  const int m0 = (rem >> 3) * 64, n0 = (rem & 7) * 64;
  const int tid = threadIdx.x;
  const int lane = tid & 63, wave = tid >> 6;
  const int wm = (wave >> 1) * 32, wn = (wave & 1) * 32;
  const ushort* Ab = P.probs_bf + (size_t)b * NN * NN;
  const ushort* Bb = P.UT + (size_t)b * DD * NN;
  f32x4 acc[2][2] = {};
  const int fm = lane & 15, quad = lane >> 4;
  for (int k0 = 0; k0 < NN; k0 += 64) {
#pragma unroll
    for (int t = 0; t < 2; ++t) {
      const int idx = tid + t * 256;
      const int r = idx >> 3, c8 = idx & 7;
      const int g = c8 ^ (r & 7);
      GLDS(Ab + (size_t)(m0 + r) * NN + k0 + g * 8, As + idx * 8);
      GLDS(Bb + (size_t)(n0 + r) * NN + k0 + g * 8, Bs + idx * 8);
    }
    __syncthreads();
#pragma unroll
    for (int s = 0; s < 2; ++s) {
      bf16x8 af[2], bfr[2];
#pragma unroll
      for (int tm = 0; tm < 2; ++tm) {
        const int row = wm + tm * 16 + fm;
        const int c8 = (s * 4 + quad) ^ (row & 7);
        af[tm] = *(const bf16x8*)&As[row * 64 + c8 * 8];
      }
#pragma unroll
      for (int tn = 0; tn < 2; ++tn) {
        const int row = wn + tn * 16 + fm;
        const int c8 = (s * 4 + quad) ^ (row & 7);
        bfr[tn] = *(const bf16x8*)&Bs[row * 64 + c8 * 8];
      }
#pragma unroll
      for (int tm = 0; tm < 2; ++tm)
#pragma unroll
        for (int tn = 0; tn < 2; ++tn)
          acc[tm][tn] = __builtin_amdgcn_mfma_f32_16x16x32_bf16(
              af[tm], bfr[tn], acc[tm][tn], 0, 0, 0);
    }
    __syncthreads();
  }
#pragma unroll
  for (int tm = 0; tm < 2; ++tm)
#pragma unroll
    for (int tn = 0; tn < 2; ++tn) {
      const int col = n0 + wn + tn * 16 + fm;
#pragma unroll
      for (int r = 0; r < 4; ++r) {
        const int row = m0 + wm + tm * 16 + quad * 4 + r;
        P.ctxt_bf[(size_t)b * NN * DD + (size_t)row * DD + col] = f2bf(acc[tm][tn][r]);
      }
    }
}

// ---- gate GEMM + sigmoid/blend; writes Uout fp32 + Ubf_out + UT; vb in [0,256) ----
__device__ void gate_phase(const KP& P, const ushort* __restrict__ Ubf,
                           const float* __restrict__ Uf, float* __restrict__ Uout,
                           ushort* __restrict__ UbfOut, int vb, char* smem) {
  ushort* As = (ushort*)smem;
  ushort* Bs = (ushort*)(smem + 8192);
  ushort (*Tt)[66] = (ushort(*)[66])(smem + 16384);
  const int b = vb >> 7;
  const int rem = vb & 127;
  const int m0 = (rem >> 3) * 64, n0 = (rem & 7) * 64;
  const int tid = threadIdx.x;
  const int lane = tid & 63, wave = tid >> 6;
  const int wm = (wave >> 1) * 32, wn = (wave & 1) * 32;
  f32x4 acc[2][2] = {};
  const int fm = lane & 15, quad = lane >> 4;
  for (int k0 = 0; k0 < 2 * DD; k0 += 64) {
    const ushort* Abase = (k0 < DD) ? (Ubf + (size_t)b * NN * DD)
                                    : (P.ctxt_bf + (size_t)b * NN * DD);
    const int kc = k0 & (DD - 1);
#pragma unroll
    for (int t = 0; t < 2; ++t) {
      const int idx = tid + t * 256;
      const int r = idx >> 3, c8 = idx & 7;
      const int g = c8 ^ (r & 7);
      GLDS(Abase + (size_t)(m0 + r) * DD + kc + g * 8, As + idx * 8);
      GLDS(P.WgT + (size_t)(n0 + r) * (2 * DD) + k0 + g * 8, Bs + idx * 8);
    }
    __syncthreads();
#pragma unroll
    for (int s = 0; s < 2; ++s) {
      bf16x8 af[2], bfr[2];
#pragma unroll
      for (int tm = 0; tm < 2; ++tm) {
        const int row = wm + tm * 16 + fm;
        const int c8 = (s * 4 + quad) ^ (row & 7);
        af[tm] = *(const bf16x8*)&As[row * 64 + c8 * 8];
      }
#pragma unroll
      for (int tn = 0; tn < 2; ++tn) {
        const int row = wn + tn * 16 + fm;
        const int c8 = (s * 4 + quad) ^ (row & 7);
        bfr[tn] = *(const bf16x8*)&Bs[row * 64 + c8 * 8];
      }
#pragma unroll
      for (int tm = 0; tm < 2; ++tm)
#pragma unroll
        for (int tn = 0; tn < 2; ++tn)
          acc[tm][tn] = __builtin_amdgcn_mfma_f32_16x16x32_bf16(
              af[tm], bfr[tn], acc[tm][tn], 0, 0, 0);
    }
    __syncthreads();
  }
#pragma unroll
  for (int tm = 0; tm < 2; ++tm)
#pragma unroll
    for (int tn = 0; tn < 2; ++tn) {
      const int cl = wn + tn * 16 + fm;
      const int col = n0 + cl;
      const float bgv = P.b_gate[col];
#pragma unroll
      for (int r = 0; r < 4; ++r) {
        const int rl = wm + tm * 16 + quad * 4 + r;
        const int row = m0 + rl;
        const size_t off = (size_t)b * NN * DD + (size_t)row * DD + col;
        const float g = 1.f / (1.f + __expf(-(acc[tm][tn][r] + bgv)));
        const float cv = __uint_as_float(((uint32_t)P.ctxt_bf[off]) << 16);
        const float o = g * Uf[off] + (1.f - g) * cv;
        Uout[off] = o;
        const ushort ob = f2bf(o);
        UbfOut[off] = ob;
        Tt[rl][cl] = ob;
      }
    }
  __syncthreads();
#pragma unroll
  for (int p = 0; p < 4; ++p) {
    const int cl = (tid >> 4) + p * 16;
    const int rl = (tid & 15) * 4;
    ushort4 o;
    o.x = Tt[rl + 0][cl]; o.y = Tt[rl + 1][cl];
    o.z = Tt[rl + 2][cl]; o.w = Tt[rl + 3][cl];
    *(ushort4*)&P.UT[((size_t)b * DD + n0 + cl) * NN + m0 + rl] = o;
  }
  __syncthreads();
}

// ================= single persistent kernel, software grid barrier =================
__global__ __launch_bounds__(256, 2) void fused_all(KP P) {
  __shared__ __align__(16) char smem[39264];
  const int bid = blockIdx.x;
  const int tid = threadIdx.x;

  // ---- Phase A (independent): WgT conv, update->Ubf0+UT conv, cand copy, lr0 ----
  for (int vb = bid; vb < 384; vb += GRID) {
    if (vb < 128) {
      conv_tile(P.Wg, nullptr, P.WgT, 2 * DD, DD, (vb >> 3) * 64, (vb & 7) * 64,
                smem);
    } else {
      const int t = vb - 128, b = t >> 7, rem = t & 127;
      conv_tile(P.update + (size_t)b * NN * DD, P.Ubf0 + (size_t)b * NN * DD,
                P.UT + (size_t)b * DD * NN, NN, DD, (rem >> 3) * 64,
                (rem & 7) * 64, smem);
    }
  }
  lr_phase(P, P.update, bid, smem);
  {
    const float4* c4 = (const float4*)P.cand;
    float4* o4 = (float4*)P.out;
    for (int idx = bid * 256 + tid; idx < NB * MM * DD / 4; idx += GRID * 256)
      o4[idx] = c4[idx];
  }
  gsync(P.bar);

  for (int it = 0; it < 2; ++it) {
    score_phase(P, bid, smem);
    gsync(P.bar);
    if (bid < 256) ctxt_phase(P, bid, smem);
    gsync(P.bar);
    const float* Uf = it ? P.upd1 : P.update;
    float* Uout = it ? P.upd2 : P.upd1;
    const ushort* Ubf_in = it ? P.Ubf1 : P.Ubf0;
    ushort* Ubf_out = it ? P.Ubf0 : P.Ubf1;
    if (bid < 256) gate_phase(P, Ubf_in, Uf, Uout, Ubf_out, bid, smem);
    gsync(P.bar);
    if (it == 0) {
      lr_phase(P, P.upd1, bid, smem);
      gsync(P.bar);
    }
  }

  // ---- final: copy upd2 into out tail + scatter into cand region ----
  {
    const float4* u4 = (const float4*)P.upd2;
    float4* o4 = (float4*)P.out + (size_t)NB * MM * DD / 4;
    for (int idx = bid * 256 + tid; idx < NB * NN * DD / 4; idx += GRID * 256)
      o4[idx] = u4[idx];
    for (int row = bid; row < NB * NN; row += GRID) {
      const int b = row >> 10, i = row & 1023;
      if (i < P.span_len[b] && tid < 128) {
        const int dst = P.prune[row];
        const float4* src = (const float4*)(P.upd2 + (size_t)row * DD);
        float4* d = (float4*)(P.out + ((size_t)b * MM + dst) * DD);
        d[tid] = src[tid];
      }
    }
  }
}

extern "C" void kernel_launch(void* const* d_in, const int* in_sizes, int n_in,
                              void* d_out, int out_size, void* d_ws, size_t ws_size,
                              hipStream_t stream) {
  KP p;
  p.update = (const float*)d_in[0];
  p.mask = (const float*)d_in[1];
  p.cand = (const float*)d_in[2];
  p.span_begin = (const int*)d_in[3];
  p.prune = (const int*)d_in[5];
  p.span_len = (const int*)d_in[6];
  p.Wl = (const float*)d_in[7];
  p.Wr = (const float*)d_in[8];
  p.b_h = (const float*)d_in[9];
  p.dist_emb = (const float*)d_in[10];
  p.v_out = (const float*)d_in[11];
  p.Wg = (const float*)d_in[13];
  p.b_gate = (const float*)d_in[14];
  p.out = (float*)d_out;

  char* w = (char*)d_ws;
  p.bar = (int*)w;         w += 256;                        // barrier state
  p.left = (float*)w;      w += (size_t)NB * NN * HH * 4;   // 512 KB
  p.right_bf = (ushort*)w; w += (size_t)NB * NN * HH * 2;   // 256 KB
  p.probs_bf = (ushort*)w; w += (size_t)NB * NN * NN * 2;   // 4 MB
  p.ctxt_bf = (ushort*)w;  w += (size_t)NB * NN * DD * 2;   // 2 MB
  p.upd1 = (float*)w;      w += (size_t)NB * NN * DD * 4;   // 4 MB
  p.upd2 = (float*)w;      w += (size_t)NB * NN * DD * 4;   // 4 MB
  p.Ubf0 = (ushort*)w;     w += (size_t)NB * NN * DD * 2;   // 2 MB
  p.Ubf1 = (ushort*)w;     w += (size_t)NB * NN * DD * 2;   // 2 MB
  p.UT = (ushort*)w;       w += (size_t)NB * NN * DD * 2;   // 2 MB
  p.WgT = (ushort*)w;      w += (size_t)2 * DD * DD * 2;    // 1 MB

  hipMemsetAsync(d_ws, 0, 256, stream);     // zero barrier state (poison-safe)
  fused_all<<<dim3(GRID), dim3(256), 0, stream>>>(p);
}

// Round 10
// 241.226 us; speedup vs baseline: 3.7881x; 3.7881x over previous
//
#include <hip/hip_runtime.h>
#include <cstdint>

#define NB 2
#define NN 1024
#define MM 2048
#define DD 512
#define HH 64
#define ST 68          // padded LDS stride (floats)
#define STB 72         // padded LDS stride (ushorts)

typedef __attribute__((ext_vector_type(8))) short bf16x8;
typedef __attribute__((ext_vector_type(4))) float f32x4;

__device__ inline ushort f2bf(float x) {
  union { float f; uint32_t u; } v; v.f = x;
  uint32_t u = v.u;
  u += 0x7FFF + ((u >> 16) & 1);      // RNE
  return (ushort)(u >> 16);
}
__device__ inline float bflo(uint32_t d) { return __uint_as_float(d << 16); }
__device__ inline float bfhi(uint32_t d) { return __uint_as_float(d & 0xFFFF0000u); }

#define GLDS(gp, lp) \
  __builtin_amdgcn_global_load_lds( \
      (const __attribute__((address_space(1))) void*)(gp), \
      (__attribute__((address_space(3))) void*)(lp), 16, 0, 0)

// ==== prep: WgT conv + update->(Ubf0,UT) conv + cand->out copy + lr0 ====
// 512 blocks. Replaces 3 kernels (conv_t x2 + lr) + out_copy's cand half.
__global__ __launch_bounds__(256) void prep_kernel(
    const float* __restrict__ Wg, ushort* __restrict__ WgT,
    const float* __restrict__ update, ushort* __restrict__ Ubf0,
    ushort* __restrict__ UT, const float* __restrict__ cand,
    float* __restrict__ out, const float* __restrict__ Wl,
    const float* __restrict__ Wr, float* __restrict__ left,
    ushort* __restrict__ right_bf) {
  __shared__ __align__(16) char smem[16640];
  const int bid = blockIdx.x;
  const int tid = threadIdx.x;
  const int tx = tid & 15, ty = tid >> 4;

  // ---- conv work: 128 Wg tiles + 256 update tiles (blocks 0..383) ----
  if (bid < 384) {
    const float* in;
    ushort* out_row;
    ushort* out_T;
    int R, C, r0, c0;
    if (bid < 128) {
      in = Wg; out_row = nullptr; out_T = WgT;
      R = 2 * DD; C = DD; r0 = (bid >> 3) * 64; c0 = (bid & 7) * 64;
    } else {
      const int t = bid - 128, b = t >> 7, rem = t & 127;
      in = update + (size_t)b * NN * DD;
      out_row = Ubf0 + (size_t)b * NN * DD;
      out_T = UT + (size_t)b * DD * NN;
      R = NN; C = DD; r0 = (rem >> 3) * 64; c0 = (rem & 7) * 64;
    }
    float (*tile)[65] = (float(*)[65])smem;
#pragma unroll
    for (int p = 0; p < 4; ++p) {
      const int r = ty + p * 16;
      const float4 v = *(const float4*)&in[(size_t)(r0 + r) * C + c0 + tx * 4];
      tile[r][tx * 4 + 0] = v.x; tile[r][tx * 4 + 1] = v.y;
      tile[r][tx * 4 + 2] = v.z; tile[r][tx * 4 + 3] = v.w;
      if (out_row) {
        ushort4 o = make_ushort4(f2bf(v.x), f2bf(v.y), f2bf(v.z), f2bf(v.w));
        *(ushort4*)&out_row[(size_t)(r0 + r) * C + c0 + tx * 4] = o;
      }
    }
    __syncthreads();
#pragma unroll
    for (int p = 0; p < 4; ++p) {
      const int rr = ty + p * 16;
      ushort4 o;
      o.x = f2bf(tile[tx * 4 + 0][rr]);
      o.y = f2bf(tile[tx * 4 + 1][rr]);
      o.z = f2bf(tile[tx * 4 + 2][rr]);
      o.w = f2bf(tile[tx * 4 + 3][rr]);
      *(ushort4*)&out_T[(size_t)(c0 + rr) * R + r0 + tx * 4] = o;
    }
    __syncthreads();
  }

  // ---- lr0: 4 rows per block (all 512 blocks) ----
  {
    float (*u)[DD] = (float(*)[DD])smem;    // 8 KB
    const float4* Uv = (const float4*)(update + (size_t)bid * 4 * DD);
    float4* uv = (float4*)&u[0][0];
#pragma unroll
    for (int t = 0; t < 2; ++t) uv[tid + t * 256] = Uv[tid + t * 256];
    __syncthreads();
    const int h = tid & 63;
    const int isR = (tid >> 6) & 1;
    const int rsel = tid >> 7;
    const float* __restrict__ W = isR ? Wr : Wl;
    float acc[2] = {0.f, 0.f};
    for (int k0 = 0; k0 < DD; k0 += 4) {
      float w0 = W[(k0 + 0) * HH + h];
      float w1 = W[(k0 + 1) * HH + h];
      float w2 = W[(k0 + 2) * HH + h];
      float w3 = W[(k0 + 3) * HH + h];
#pragma unroll
      for (int r = 0; r < 2; ++r) {
        float4 u4 = *(const float4*)&u[rsel + r * 2][k0];
        acc[r] = fmaf(u4.w, w3, fmaf(u4.z, w2, fmaf(u4.y, w1, fmaf(u4.x, w0, acc[r]))));
      }
    }
    if (isR) {
#pragma unroll
      for (int r = 0; r < 2; ++r)
        right_bf[(size_t)(bid * 4 + rsel + r * 2) * HH + h] = f2bf(acc[r]);
    } else {
#pragma unroll
      for (int r = 0; r < 2; ++r)
        left[(size_t)(bid * 4 + rsel + r * 2) * HH + h] = acc[r];
    }
  }

  // ---- cand -> out head copy (8 MB, grid-stride) ----
  {
    const float4* c4 = (const float4*)cand;
    float4* o4 = (float4*)out;
    for (int idx = bid * 256 + tid; idx < NB * MM * DD / 4; idx += 512 * 256)
      o4[idx] = c4[idx];
  }
}

// ---- standalone lr (iteration 1): 512 blocks x 4 rows ----
__global__ __launch_bounds__(256) void lr_kernel(
    const float* __restrict__ U, const float* __restrict__ Wl,
    const float* __restrict__ Wr, float* __restrict__ left,
    ushort* __restrict__ right_bf) {
  __shared__ float u[4][DD];
  const int bid = blockIdx.x;
  const int tid = threadIdx.x;
  const float4* Uv = (const float4*)(U + (size_t)bid * 4 * DD);
  float4* uv = (float4*)&u[0][0];
#pragma unroll
  for (int t = 0; t < 2; ++t) uv[tid + t * 256] = Uv[tid + t * 256];
  __syncthreads();
  const int h = tid & 63;
  const int isR = (tid >> 6) & 1;
  const int rsel = tid >> 7;
  const float* __restrict__ W = isR ? Wr : Wl;
  float acc[2] = {0.f, 0.f};
  for (int k0 = 0; k0 < DD; k0 += 4) {
    float w0 = W[(k0 + 0) * HH + h];
    float w1 = W[(k0 + 1) * HH + h];
    float w2 = W[(k0 + 2) * HH + h];
    float w3 = W[(k0 + 3) * HH + h];
#pragma unroll
    for (int r = 0; r < 2; ++r) {
      float4 u4 = *(const float4*)&u[rsel + r * 2][k0];
      acc[r] = fmaf(u4.w, w3, fmaf(u4.z, w2, fmaf(u4.y, w1, fmaf(u4.x, w0, acc[r]))));
    }
  }
  if (isR) {
#pragma unroll
    for (int r = 0; r < 2; ++r)
      right_bf[(size_t)(bid * 4 + rsel + r * 2) * HH + h] = f2bf(acc[r]);
  } else {
#pragma unroll
    for (int r = 0; r < 2; ++r)
      left[(size_t)(bid * 4 + rsel + r * 2) * HH + h] = acc[r];
  }
}

// ---- fused score + softmax -> bf16 probs. 4 rows/block (1 row per wave). ----
__global__ __launch_bounds__(256) void score_softmax(
    const float* __restrict__ left, const ushort* __restrict__ right_bf,
    const int* __restrict__ span_begin, const float* __restrict__ mask,
    const float* __restrict__ dist_emb, const float* __restrict__ b_h,
    const float* __restrict__ v_out, ushort* __restrict__ probs_bf) {
  __shared__ ushort Rt[64][STB];
  __shared__ ushort LDb[4][10][STB];
  __shared__ float Dbh[10][ST];
  __shared__ float Lt[4][ST];
  __shared__ float Sc[4][NN];
  __shared__ int sbj[NN];
  const int b = blockIdx.y;
  const int r0 = blockIdx.x * 4;
  const int tid = threadIdx.x;
  const int wave = tid >> 6, lane = tid & 63;
  const int row = r0 + wave;

  for (int f = tid; f < 160; f += 256) {
    int bk = f >> 4, h4 = f & 15;
    float4 d = *(const float4*)&dist_emb[bk * HH + h4 * 4];
    float4 bh = *(const float4*)&b_h[h4 * 4];
    d.x += bh.x; d.y += bh.y; d.z += bh.z; d.w += bh.w;
    *(float4*)&Dbh[bk][h4 * 4] = d;
  }
  if (tid < 64) {
    int r = tid >> 4, h4 = tid & 15;
    *(float4*)&Lt[r][h4 * 4] =
        *(const float4*)&left[((size_t)b * NN + r0 + r) * HH + h4 * 4];
  }
  for (int t = tid; t < NN; t += 256) sbj[t] = span_begin[b * NN + t];
  __syncthreads();
  for (int f = tid; f < 2560; f += 256) {
    int i = f / 640;
    int rem = f - i * 640;
    int bk = rem >> 6, h = rem & 63;
    LDb[i][bk][h] = f2bf(Lt[i][h] + Dbh[bk][h]);
  }
  float4 vr[16];
#pragma unroll
  for (int hq = 0; hq < 16; ++hq) vr[hq] = *(const float4*)&v_out[hq * 4];
  const int my_sbi = span_begin[(size_t)b * NN + row];
  const float* maskrow = mask + ((size_t)b * NN + row) * NN;

#pragma unroll 1
  for (int c = 0; c < 16; ++c) {
    __syncthreads();
#pragma unroll
    for (int t = 0; t < 2; ++t) {
      const int f = tid + t * 256;
      const int r = f >> 3, u8 = f & 7;
      *(bf16x8*)&Rt[r][u8 * 8] =
          *(const bf16x8*)&right_bf[((size_t)b * NN + c * 64 + r) * HH + u8 * 8];
    }
    __syncthreads();
    int d = sbj[c * 64 + lane] - my_sbi;
    d = d < 0 ? -d : d;
    const int bk =
        d <= 4 ? d : (d <= 7 ? 5 : (d <= 15 ? 6 : (d <= 31 ? 7 : (d <= 63 ? 8 : 9))));
    const ushort* zp = &LDb[wave][bk][0];
    const ushort* rp = &Rt[lane][0];
    float acc0 = 0.f, acc1 = 0.f;
#pragma unroll
    for (int oct = 0; oct < 8; oct += 2) {
      {
        const uint4 zd = *(const uint4*)&zp[oct * 8];
        const uint4 rd = *(const uint4*)&rp[oct * 8];
        const float4 v0 = vr[2 * oct], v1 = vr[2 * oct + 1];
        acc0 = fmaf(fmaxf(bflo(zd.x) + bflo(rd.x), 0.f), v0.x, acc0);
        acc0 = fmaf(fmaxf(bfhi(zd.x) + bfhi(rd.x), 0.f), v0.y, acc0);
        acc0 = fmaf(fmaxf(bflo(zd.y) + bflo(rd.y), 0.f), v0.z, acc0);
        acc0 = fmaf(fmaxf(bfhi(zd.y) + bfhi(rd.y), 0.f), v0.w, acc0);
        acc0 = fmaf(fmaxf(bflo(zd.z) + bflo(rd.z), 0.f), v1.x, acc0);
        acc0 = fmaf(fmaxf(bfhi(zd.z) + bfhi(rd.z), 0.f), v1.y, acc0);
        acc0 = fmaf(fmaxf(bflo(zd.w) + bflo(rd.w), 0.f), v1.z, acc0);
        acc0 = fmaf(fmaxf(bfhi(zd.w) + bfhi(rd.w), 0.f), v1.w, acc0);
      }
      {
        const uint4 zd = *(const uint4*)&zp[(oct + 1) * 8];
        const uint4 rd = *(const uint4*)&rp[(oct + 1) * 8];
        const float4 v0 = vr[2 * oct + 2], v1 = vr[2 * oct + 3];
        acc1 = fmaf(fmaxf(bflo(zd.x) + bflo(rd.x), 0.f), v0.x, acc1);
        acc1 = fmaf(fmaxf(bfhi(zd.x) + bfhi(rd.x), 0.f), v0.y, acc1);
        acc1 = fmaf(fmaxf(bflo(zd.y) + bflo(rd.y), 0.f), v0.z, acc1);
        acc1 = fmaf(fmaxf(bfhi(zd.y) + bfhi(rd.y), 0.f), v0.w, acc1);
        acc1 = fmaf(fmaxf(bflo(zd.z) + bflo(rd.z), 0.f), v1.x, acc1);
        acc1 = fmaf(fmaxf(bfhi(zd.z) + bfhi(rd.z), 0.f), v1.y, acc1);
        acc1 = fmaf(fmaxf(bflo(zd.w) + bflo(rd.w), 0.f), v1.z, acc1);
        acc1 = fmaf(fmaxf(bfhi(zd.w) + bfhi(rd.w), 0.f), v1.w, acc1);
      }
    }
    const float mval = maskrow[c * 64 + lane];
    Sc[wave][c * 64 + lane] = (acc0 + acc1) - (1.0f - mval) * 1e23f;
  }
  float mx = -3.0e38f;
#pragma unroll
  for (int c = 0; c < 16; ++c) mx = fmaxf(mx, Sc[wave][c * 64 + lane]);
#pragma unroll
  for (int off = 32; off; off >>= 1) mx = fmaxf(mx, __shfl_xor(mx, off));
  float sum = 0.f;
#pragma unroll
  for (int c = 0; c < 16; ++c) {
    const float e = __expf(Sc[wave][c * 64 + lane] - mx);
    Sc[wave][c * 64 + lane] = e;
    sum += e;
  }
#pragma unroll
  for (int off = 32; off; off >>= 1) sum += __shfl_xor(sum, off);
  const float inv = 1.0f / sum;
  ushort* prow = probs_bf + ((size_t)b * NN + row) * NN;
#pragma unroll
  for (int c = 0; c < 16; ++c)
    prow[c * 64 + lane] = f2bf(Sc[wave][c * 64 + lane] * inv);
}

// -------- ctxt(bf16) = P @ U via bf16 MFMA. A=probs_bf, B=UT --------
__global__ __launch_bounds__(256) void gemm_ctxt_mfma(
    const ushort* __restrict__ Pbf, const ushort* __restrict__ UT,
    ushort* __restrict__ Cbf) {
  __shared__ ushort As[64 * 64];
  __shared__ ushort Bs[64 * 64];
  const int b = blockIdx.z;
  const int m0 = blockIdx.y * 64, n0 = blockIdx.x * 64;
  const int tid = threadIdx.x;
  const int lane = tid & 63, wave = tid >> 6;
  const int wm = (wave >> 1) * 32, wn = (wave & 1) * 32;
  const ushort* Ab = Pbf + (size_t)b * NN * NN;
  const ushort* Bb = UT + (size_t)b * DD * NN;
  f32x4 acc[2][2] = {};
  const int fm = lane & 15, quad = lane >> 4;
  for (int k0 = 0; k0 < NN; k0 += 64) {
#pragma unroll
    for (int t = 0; t < 2; ++t) {
      const int idx = tid + t * 256;
      const int r = idx >> 3, c8 = idx & 7;
      const int g = c8 ^ (r & 7);
      GLDS(Ab + (size_t)(m0 + r) * NN + k0 + g * 8, As + idx * 8);
      GLDS(Bb + (size_t)(n0 + r) * NN + k0 + g * 8, Bs + idx * 8);
    }
    __syncthreads();
#pragma unroll
    for (int s = 0; s < 2; ++s) {
      bf16x8 af[2], bfr[2];
#pragma unroll
      for (int tm = 0; tm < 2; ++tm) {
        const int row = wm + tm * 16 + fm;
        const int c8 = (s * 4 + quad) ^ (row & 7);
        af[tm] = *(const bf16x8*)&As[row * 64 + c8 * 8];
      }
#pragma unroll
      for (int tn = 0; tn < 2; ++tn) {
        const int row = wn + tn * 16 + fm;
        const int c8 = (s * 4 + quad) ^ (row & 7);
        bfr[tn] = *(const bf16x8*)&Bs[row * 64 + c8 * 8];
      }
#pragma unroll
      for (int tm = 0; tm < 2; ++tm)
#pragma unroll
        for (int tn = 0; tn < 2; ++tn)
          acc[tm][tn] = __builtin_amdgcn_mfma_f32_16x16x32_bf16(
              af[tm], bfr[tn], acc[tm][tn], 0, 0, 0);
    }
    __syncthreads();
  }
#pragma unroll
  for (int tm = 0; tm < 2; ++tm)
#pragma unroll
    for (int tn = 0; tn < 2; ++tn) {
      const int col = n0 + wn + tn * 16 + fm;
#pragma unroll
      for (int r = 0; r < 4; ++r) {
        const int row = m0 + wm + tm * 16 + quad * 4 + r;
        Cbf[(size_t)b * NN * DD + (size_t)row * DD + col] = f2bf(acc[tm][tn][r]);
      }
    }
}

// -------- gate GEMM + sigmoid/blend. final=0: writes Uout fp32 + Ubf_out + UT.
// final=1: writes out's update region directly + scatters into out's cand region. --------
__global__ __launch_bounds__(256) void gemm_gate_mfma(
    const ushort* __restrict__ Ubf, const ushort* __restrict__ Cbf,
    const ushort* __restrict__ WgT, const float* __restrict__ bg,
    const float* __restrict__ Uf, float* __restrict__ Uout,
    ushort* __restrict__ UbfOut, ushort* __restrict__ UTOut,
    const int* __restrict__ prune, const int* __restrict__ span_len,
    float* __restrict__ out_cand, int final_it) {
  __shared__ ushort As[64 * 64];
  __shared__ ushort Bs[64 * 64];
  __shared__ ushort Tt[64][66];
  const int b = blockIdx.z;
  const int m0 = blockIdx.y * 64, n0 = blockIdx.x * 64;
  const int tid = threadIdx.x;
  const int lane = tid & 63, wave = tid >> 6;
  const int wm = (wave >> 1) * 32, wn = (wave & 1) * 32;
  f32x4 acc[2][2] = {};
  const int fm = lane & 15, quad = lane >> 4;
  for (int k0 = 0; k0 < 2 * DD; k0 += 64) {
    const ushort* Abase = (k0 < DD) ? (Ubf + (size_t)b * NN * DD)
                                    : (Cbf + (size_t)b * NN * DD);
    const int kc = k0 & (DD - 1);
#pragma unroll
    for (int t = 0; t < 2; ++t) {
      const int idx = tid + t * 256;
      const int r = idx >> 3, c8 = idx & 7;
      const int g = c8 ^ (r & 7);
      GLDS(Abase + (size_t)(m0 + r) * DD + kc + g * 8, As + idx * 8);
      GLDS(WgT + (size_t)(n0 + r) * (2 * DD) + k0 + g * 8, Bs + idx * 8);
    }
    __syncthreads();
#pragma unroll
    for (int s = 0; s < 2; ++s) {
      bf16x8 af[2], bfr[2];
#pragma unroll
      for (int tm = 0; tm < 2; ++tm) {
        const int row = wm + tm * 16 + fm;
        const int c8 = (s * 4 + quad) ^ (row & 7);
        af[tm] = *(const bf16x8*)&As[row * 64 + c8 * 8];
      }
#pragma unroll
      for (int tn = 0; tn < 2; ++tn) {
        const int row = wn + tn * 16 + fm;
        const int c8 = (s * 4 + quad) ^ (row & 7);
        bfr[tn] = *(const bf16x8*)&Bs[row * 64 + c8 * 8];
      }
#pragma unroll
      for (int tm = 0; tm < 2; ++tm)
#pragma unroll
        for (int tn = 0; tn < 2; ++tn)
          acc[tm][tn] = __builtin_amdgcn_mfma_f32_16x16x32_bf16(
              af[tm], bfr[tn], acc[tm][tn], 0, 0, 0);
    }
    __syncthreads();
  }
  const int slen = span_len[b];
#pragma unroll
  for (int tm = 0; tm < 2; ++tm)
#pragma unroll
    for (int tn = 0; tn < 2; ++tn) {
      const int cl = wn + tn * 16 + fm;
      const int col = n0 + cl;
      const float bgv = bg[col];
#pragma unroll
      for (int r = 0; r < 4; ++r) {
        const int rl = wm + tm * 16 + quad * 4 + r;
        const int row = m0 + rl;
        const size_t off = (size_t)b * NN * DD + (size_t)row * DD + col;
        const float g = 1.f / (1.f + __expf(-(acc[tm][tn][r] + bgv)));
        const float cv = __uint_as_float(((uint32_t)Cbf[off]) << 16);
        const float o = g * Uf[off] + (1.f - g) * cv;
        Uout[off] = o;
        if (final_it) {
          if (row < slen) {
            const int dst = prune[b * NN + row];
            out_cand[((size_t)b * MM + dst) * DD + col] = o;
          }
        } else {
          const ushort ob = f2bf(o);
          UbfOut[off] = ob;
          Tt[rl][cl] = ob;
        }
      }
    }
  if (!final_it) {
    __syncthreads();
#pragma unroll
    for (int p = 0; p < 4; ++p) {
      const int cl = (tid >> 4) + p * 16;
      const int rl = (tid & 15) * 4;
      ushort4 o;
      o.x = Tt[rl + 0][cl]; o.y = Tt[rl + 1][cl];
      o.z = Tt[rl + 2][cl]; o.w = Tt[rl + 3][cl];
      *(ushort4*)&UTOut[((size_t)b * DD + n0 + cl) * NN + m0 + rl] = o;
    }
  }
}

extern "C" void kernel_launch(void* const* d_in, const int* in_sizes, int n_in,
                              void* d_out, int out_size, void* d_ws, size_t ws_size,
                              hipStream_t stream) {
  const float* update = (const float*)d_in[0];
  const float* mask = (const float*)d_in[1];
  const float* cand = (const float*)d_in[2];
  const int* span_begin = (const int*)d_in[3];
  const int* prune = (const int*)d_in[5];
  const int* span_len = (const int*)d_in[6];
  const float* Wl = (const float*)d_in[7];
  const float* Wr = (const float*)d_in[8];
  const float* b_h = (const float*)d_in[9];
  const float* dist_emb = (const float*)d_in[10];
  const float* v_out = (const float*)d_in[11];
  const float* Wg = (const float*)d_in[13];
  const float* b_gate = (const float*)d_in[14];

  char* w = (char*)d_ws;
  float* left = (float*)w;        w += (size_t)NB * NN * HH * 4;   // 512 KB
  ushort* right_bf = (ushort*)w;  w += (size_t)NB * NN * HH * 2;   // 256 KB
  ushort* probs_bf = (ushort*)w;  w += (size_t)NB * NN * NN * 2;   // 4 MB
  ushort* ctxt_bf = (ushort*)w;   w += (size_t)NB * NN * DD * 2;   // 2 MB
  float* upd1 = (float*)w;        w += (size_t)NB * NN * DD * 4;   // 4 MB
  ushort* Ubf0 = (ushort*)w;      w += (size_t)NB * NN * DD * 2;   // 2 MB
  ushort* Ubf1 = (ushort*)w;      w += (size_t)NB * NN * DD * 2;   // 2 MB
  ushort* UT = (ushort*)w;        w += (size_t)NB * NN * DD * 2;   // 2 MB
  ushort* WgT = (ushort*)w;       w += (size_t)2 * DD * DD * 2;    // 1 MB

  float* out = (float*)d_out;
  float* out_upd = out + (size_t)NB * MM * DD;   // update output region

  // 1: prep (conv WgT + conv update->Ubf0/UT + cand copy + lr0)
  prep_kernel<<<512, 256, 0, stream>>>(Wg, WgT, update, Ubf0, UT, cand, out,
                                       Wl, Wr, left, right_bf);
  // iteration 0
  score_softmax<<<dim3(NN / 4, NB), 256, 0, stream>>>(
      left, right_bf, span_begin, mask, dist_emb, b_h, v_out, probs_bf);
  gemm_ctxt_mfma<<<dim3(8, 16, NB), 256, 0, stream>>>(probs_bf, UT, ctxt_bf);
  gemm_gate_mfma<<<dim3(8, 16, NB), 256, 0, stream>>>(
      Ubf0, ctxt_bf, WgT, b_gate, update, upd1, Ubf1, UT,
      prune, span_len, out, 0);
  // iteration 1
  lr_kernel<<<512, 256, 0, stream>>>(upd1, Wl, Wr, left, right_bf);
  score_softmax<<<dim3(NN / 4, NB), 256, 0, stream>>>(
      left, right_bf, span_begin, mask, dist_emb, b_h, v_out, probs_bf);
  gemm_ctxt_mfma<<<dim3(8, 16, NB), 256, 0, stream>>>(probs_bf, UT, ctxt_bf);
  // final gate: writes out's update region + scatters into out's cand region
  gemm_gate_mfma<<<dim3(8, 16, NB), 256, 0, stream>>>(
      Ubf1, ctxt_bf, WgT, b_gate, upd1, out_upd, nullptr, nullptr,
      prune, span_len, out, 1);
}

// Round 11
// 232.073 us; speedup vs baseline: 3.9375x; 1.0394x over previous
//
#include <hip/hip_runtime.h>
#include <cstdint>

#define NB 2
#define NN 1024
#define MM 2048
#define DD 512
#define HH 64
#define ST 68          // padded LDS stride (floats)
#define STB 72         // padded LDS stride (ushorts)

typedef __attribute__((ext_vector_type(8))) short bf16x8;
typedef __attribute__((ext_vector_type(4))) float f32x4;

__device__ inline ushort f2bf(float x) {
  union { float f; uint32_t u; } v; v.f = x;
  uint32_t u = v.u;
  u += 0x7FFF + ((u >> 16) & 1);      // RNE
  return (ushort)(u >> 16);
}
__device__ inline float bflo(uint32_t d) { return __uint_as_float(d << 16); }
__device__ inline float bfhi(uint32_t d) { return __uint_as_float(d & 0xFFFF0000u); }

#define GLDS(gp, lp) \
  __builtin_amdgcn_global_load_lds( \
      (const __attribute__((address_space(1))) void*)(gp), \
      (__attribute__((address_space(3))) void*)(lp), 16, 0, 0)

// ==== prep: WgT conv + update->(Ubf0,UT) conv + cand->out copy + lr0 ====
__global__ __launch_bounds__(256) void prep_kernel(
    const float* __restrict__ Wg, ushort* __restrict__ WgT,
    const float* __restrict__ update, ushort* __restrict__ Ubf0,
    ushort* __restrict__ UT, const float* __restrict__ cand,
    float* __restrict__ out, const float* __restrict__ Wl,
    const float* __restrict__ Wr, float* __restrict__ left,
    ushort* __restrict__ right_bf) {
  __shared__ __align__(16) char smem[16640];
  const int bid = blockIdx.x;
  const int tid = threadIdx.x;
  const int tx = tid & 15, ty = tid >> 4;

  if (bid < 384) {
    const float* in;
    ushort* out_row;
    ushort* out_T;
    int R, C, r0, c0;
    if (bid < 128) {
      in = Wg; out_row = nullptr; out_T = WgT;
      R = 2 * DD; C = DD; r0 = (bid >> 3) * 64; c0 = (bid & 7) * 64;
    } else {
      const int t = bid - 128, b = t >> 7, rem = t & 127;
      in = update + (size_t)b * NN * DD;
      out_row = Ubf0 + (size_t)b * NN * DD;
      out_T = UT + (size_t)b * DD * NN;
      R = NN; C = DD; r0 = (rem >> 3) * 64; c0 = (rem & 7) * 64;
    }
    float (*tile)[65] = (float(*)[65])smem;
#pragma unroll
    for (int p = 0; p < 4; ++p) {
      const int r = ty + p * 16;
      const float4 v = *(const float4*)&in[(size_t)(r0 + r) * C + c0 + tx * 4];
      tile[r][tx * 4 + 0] = v.x; tile[r][tx * 4 + 1] = v.y;
      tile[r][tx * 4 + 2] = v.z; tile[r][tx * 4 + 3] = v.w;
      if (out_row) {
        ushort4 o = make_ushort4(f2bf(v.x), f2bf(v.y), f2bf(v.z), f2bf(v.w));
        *(ushort4*)&out_row[(size_t)(r0 + r) * C + c0 + tx * 4] = o;
      }
    }
    __syncthreads();
#pragma unroll
    for (int p = 0; p < 4; ++p) {
      const int rr = ty + p * 16;
      ushort4 o;
      o.x = f2bf(tile[tx * 4 + 0][rr]);
      o.y = f2bf(tile[tx * 4 + 1][rr]);
      o.z = f2bf(tile[tx * 4 + 2][rr]);
      o.w = f2bf(tile[tx * 4 + 3][rr]);
      *(ushort4*)&out_T[(size_t)(c0 + rr) * R + r0 + tx * 4] = o;
    }
    __syncthreads();
  }

  // ---- lr0: 4 rows per block ----
  {
    float (*u)[DD] = (float(*)[DD])smem;
    const float4* Uv = (const float4*)(update + (size_t)bid * 4 * DD);
    float4* uv = (float4*)&u[0][0];
#pragma unroll
    for (int t = 0; t < 2; ++t) uv[tid + t * 256] = Uv[tid + t * 256];
    __syncthreads();
    const int h = tid & 63;
    const int isR = (tid >> 6) & 1;
    const int rsel = tid >> 7;
    const float* __restrict__ W = isR ? Wr : Wl;
    float acc[2] = {0.f, 0.f};
    for (int k0 = 0; k0 < DD; k0 += 4) {
      float w0 = W[(k0 + 0) * HH + h];
      float w1 = W[(k0 + 1) * HH + h];
      float w2 = W[(k0 + 2) * HH + h];
      float w3 = W[(k0 + 3) * HH + h];
#pragma unroll
      for (int r = 0; r < 2; ++r) {
        float4 u4 = *(const float4*)&u[rsel + r * 2][k0];
        acc[r] = fmaf(u4.w, w3, fmaf(u4.z, w2, fmaf(u4.y, w1, fmaf(u4.x, w0, acc[r]))));
      }
    }
    if (isR) {
#pragma unroll
      for (int r = 0; r < 2; ++r)
        right_bf[(size_t)(bid * 4 + rsel + r * 2) * HH + h] = f2bf(acc[r]);
    } else {
#pragma unroll
      for (int r = 0; r < 2; ++r)
        left[(size_t)(bid * 4 + rsel + r * 2) * HH + h] = acc[r];
    }
  }

  // ---- cand -> out head copy ----
  {
    const float4* c4 = (const float4*)cand;
    float4* o4 = (float4*)out;
    for (int idx = bid * 256 + tid; idx < NB * MM * DD / 4; idx += 512 * 256)
      o4[idx] = c4[idx];
  }
}

// ---- standalone lr (iteration 1) ----
__global__ __launch_bounds__(256) void lr_kernel(
    const float* __restrict__ U, const float* __restrict__ Wl,
    const float* __restrict__ Wr, float* __restrict__ left,
    ushort* __restrict__ right_bf) {
  __shared__ float u[4][DD];
  const int bid = blockIdx.x;
  const int tid = threadIdx.x;
  const float4* Uv = (const float4*)(U + (size_t)bid * 4 * DD);
  float4* uv = (float4*)&u[0][0];
#pragma unroll
  for (int t = 0; t < 2; ++t) uv[tid + t * 256] = Uv[tid + t * 256];
  __syncthreads();
  const int h = tid & 63;
  const int isR = (tid >> 6) & 1;
  const int rsel = tid >> 7;
  const float* __restrict__ W = isR ? Wr : Wl;
  float acc[2] = {0.f, 0.f};
  for (int k0 = 0; k0 < DD; k0 += 4) {
    float w0 = W[(k0 + 0) * HH + h];
    float w1 = W[(k0 + 1) * HH + h];
    float w2 = W[(k0 + 2) * HH + h];
    float w3 = W[(k0 + 3) * HH + h];
#pragma unroll
    for (int r = 0; r < 2; ++r) {
      float4 u4 = *(const float4*)&u[rsel + r * 2][k0];
      acc[r] = fmaf(u4.w, w3, fmaf(u4.z, w2, fmaf(u4.y, w1, fmaf(u4.x, w0, acc[r]))));
    }
  }
  if (isR) {
#pragma unroll
    for (int r = 0; r < 2; ++r)
      right_bf[(size_t)(bid * 4 + rsel + r * 2) * HH + h] = f2bf(acc[r]);
  } else {
#pragma unroll
    for (int r = 0; r < 2; ++r)
      left[(size_t)(bid * 4 + rsel + r * 2) * HH + h] = acc[r];
  }
}

// ---- fused score + softmax -> bf16 probs. 4 rows/block, j-chunks of 128
// (16 barriers instead of 32; LDS 48.5 KB -> 3 blocks/CU for overlap). ----
__global__ __launch_bounds__(256) void score_softmax(
    const float* __restrict__ left, const ushort* __restrict__ right_bf,
    const int* __restrict__ span_begin, const float* __restrict__ mask,
    const float* __restrict__ dist_emb, const float* __restrict__ b_h,
    const float* __restrict__ v_out, ushort* __restrict__ probs_bf) {
  __shared__ ushort Rt[128][STB];      // 18.4 KB  current 128-j chunk of right
  __shared__ ushort LDb[4][10][STB];   //  5.8 KB
  __shared__ float Dbh[10][ST];        //  2.7 KB
  __shared__ float Lt[4][ST];          //  1.1 KB
  __shared__ float Sc[4][NN];          // 16.0 KB
  __shared__ int sbj[NN];              //  4.0 KB   (total ~48.5 KB)
  const int b = blockIdx.y;
  const int r0 = blockIdx.x * 4;
  const int tid = threadIdx.x;
  const int wave = tid >> 6, lane = tid & 63;
  const int row = r0 + wave;

  for (int f = tid; f < 160; f += 256) {
    int bk = f >> 4, h4 = f & 15;
    float4 d = *(const float4*)&dist_emb[bk * HH + h4 * 4];
    float4 bh = *(const float4*)&b_h[h4 * 4];
    d.x += bh.x; d.y += bh.y; d.z += bh.z; d.w += bh.w;
    *(float4*)&Dbh[bk][h4 * 4] = d;
  }
  if (tid < 64) {
    int r = tid >> 4, h4 = tid & 15;
    *(float4*)&Lt[r][h4 * 4] =
        *(const float4*)&left[((size_t)b * NN + r0 + r) * HH + h4 * 4];
  }
  for (int t = tid; t < NN; t += 256) sbj[t] = span_begin[b * NN + t];
  __syncthreads();
  for (int f = tid; f < 2560; f += 256) {
    int i = f / 640;
    int rem = f - i * 640;
    int bk = rem >> 6, h = rem & 63;
    LDb[i][bk][h] = f2bf(Lt[i][h] + Dbh[bk][h]);
  }
  float4 vr[16];
#pragma unroll
  for (int hq = 0; hq < 16; ++hq) vr[hq] = *(const float4*)&v_out[hq * 4];
  const int my_sbi = span_begin[(size_t)b * NN + row];
  const float* maskrow = mask + ((size_t)b * NN + row) * NN;

#pragma unroll 1
  for (int c = 0; c < 8; ++c) {
    __syncthreads();                   // Rt reuse boundary (covers LDb fill at c=0)
#pragma unroll
    for (int t = 0; t < 4; ++t) {
      const int f = tid + t * 256;
      const int r = f >> 3, u8 = f & 7;
      *(bf16x8*)&Rt[r][u8 * 8] =
          *(const bf16x8*)&right_bf[((size_t)b * NN + c * 128 + r) * HH + u8 * 8];
    }
    __syncthreads();
#pragma unroll 1
    for (int half = 0; half < 2; ++half) {
      const int j = c * 128 + half * 64 + lane;
      int d = sbj[j] - my_sbi;
      d = d < 0 ? -d : d;
      const int bk =
          d <= 4 ? d : (d <= 7 ? 5 : (d <= 15 ? 6 : (d <= 31 ? 7 : (d <= 63 ? 8 : 9))));
      const ushort* zp = &LDb[wave][bk][0];
      const ushort* rp = &Rt[half * 64 + lane][0];
      float acc0 = 0.f, acc1 = 0.f;
#pragma unroll
      for (int oct = 0; oct < 8; oct += 2) {
        {
          const uint4 zd = *(const uint4*)&zp[oct * 8];
          const uint4 rd = *(const uint4*)&rp[oct * 8];
          const float4 v0 = vr[2 * oct], v1 = vr[2 * oct + 1];
          acc0 = fmaf(fmaxf(bflo(zd.x) + bflo(rd.x), 0.f), v0.x, acc0);
          acc0 = fmaf(fmaxf(bfhi(zd.x) + bfhi(rd.x), 0.f), v0.y, acc0);
          acc0 = fmaf(fmaxf(bflo(zd.y) + bflo(rd.y), 0.f), v0.z, acc0);
          acc0 = fmaf(fmaxf(bfhi(zd.y) + bfhi(rd.y), 0.f), v0.w, acc0);
          acc0 = fmaf(fmaxf(bflo(zd.z) + bflo(rd.z), 0.f), v1.x, acc0);
          acc0 = fmaf(fmaxf(bfhi(zd.z) + bfhi(rd.z), 0.f), v1.y, acc0);
          acc0 = fmaf(fmaxf(bflo(zd.w) + bflo(rd.w), 0.f), v1.z, acc0);
          acc0 = fmaf(fmaxf(bfhi(zd.w) + bfhi(rd.w), 0.f), v1.w, acc0);
        }
        {
          const uint4 zd = *(const uint4*)&zp[(oct + 1) * 8];
          const uint4 rd = *(const uint4*)&rp[(oct + 1) * 8];
          const float4 v0 = vr[2 * oct + 2], v1 = vr[2 * oct + 3];
          acc1 = fmaf(fmaxf(bflo(zd.x) + bflo(rd.x), 0.f), v0.x, acc1);
          acc1 = fmaf(fmaxf(bfhi(zd.x) + bfhi(rd.x), 0.f), v0.y, acc1);
          acc1 = fmaf(fmaxf(bflo(zd.y) + bflo(rd.y), 0.f), v0.z, acc1);
          acc1 = fmaf(fmaxf(bfhi(zd.y) + bfhi(rd.y), 0.f), v0.w, acc1);
          acc1 = fmaf(fmaxf(bflo(zd.z) + bflo(rd.z), 0.f), v1.x, acc1);
          acc1 = fmaf(fmaxf(bfhi(zd.z) + bfhi(rd.z), 0.f), v1.y, acc1);
          acc1 = fmaf(fmaxf(bflo(zd.w) + bflo(rd.w), 0.f), v1.z, acc1);
          acc1 = fmaf(fmaxf(bfhi(zd.w) + bfhi(rd.w), 0.f), v1.w, acc1);
        }
      }
      const float mval = maskrow[j];
      Sc[wave][j] = (acc0 + acc1) - (1.0f - mval) * 1e23f;
    }
  }
  float mx = -3.0e38f;
#pragma unroll
  for (int c = 0; c < 16; ++c) mx = fmaxf(mx, Sc[wave][c * 64 + lane]);
#pragma unroll
  for (int off = 32; off; off >>= 1) mx = fmaxf(mx, __shfl_xor(mx, off));
  float sum = 0.f;
#pragma unroll
  for (int c = 0; c < 16; ++c) {
    const float e = __expf(Sc[wave][c * 64 + lane] - mx);
    Sc[wave][c * 64 + lane] = e;
    sum += e;
  }
#pragma unroll
  for (int off = 32; off; off >>= 1) sum += __shfl_xor(sum, off);
  const float inv = 1.0f / sum;
  ushort* prow = probs_bf + ((size_t)b * NN + row) * NN;
#pragma unroll
  for (int c = 0; c < 16; ++c)
    prow[c * 64 + lane] = f2bf(Sc[wave][c * 64 + lane] * inv);
}

// -------- ctxt(bf16) = P @ U, bf16 MFMA, 32x64 tile (512 blocks = 2/CU) --------
__global__ __launch_bounds__(256) void gemm_ctxt_mfma(
    const ushort* __restrict__ Pbf, const ushort* __restrict__ UT,
    ushort* __restrict__ Cbf) {
  __shared__ ushort As[32 * 64];       // 4 KB
  __shared__ ushort Bs[64 * 64];       // 8 KB
  const int b = blockIdx.z;
  const int m0 = blockIdx.y * 32, n0 = blockIdx.x * 64;
  const int tid = threadIdx.x;
  const int lane = tid & 63, wave = tid >> 6;
  const int wm = (wave >> 1) * 16, wn = (wave & 1) * 32;
  const ushort* Ab = Pbf + (size_t)b * NN * NN;
  const ushort* Bb = UT + (size_t)b * DD * NN;
  f32x4 acc[2] = {};
  const int fm = lane & 15, quad = lane >> 4;
  for (int k0 = 0; k0 < NN; k0 += 64) {
    {  // A: 32 rows x 8 chunks = 256 GLDS
      const int r = tid >> 3, c8 = tid & 7;
      const int g = c8 ^ (r & 7);
      GLDS(Ab + (size_t)(m0 + r) * NN + k0 + g * 8, As + tid * 8);
    }
#pragma unroll
    for (int t = 0; t < 2; ++t) {  // B: 64 rows x 8 chunks = 512 GLDS
      const int idx = tid + t * 256;
      const int r = idx >> 3, c8 = idx & 7;
      const int g = c8 ^ (r & 7);
      GLDS(Bb + (size_t)(n0 + r) * NN + k0 + g * 8, Bs + idx * 8);
    }
    __syncthreads();
#pragma unroll
    for (int s = 0; s < 2; ++s) {
      bf16x8 af, bfr[2];
      {
        const int row = wm + fm;
        const int c8 = (s * 4 + quad) ^ (row & 7);
        af = *(const bf16x8*)&As[row * 64 + c8 * 8];
      }
#pragma unroll
      for (int tn = 0; tn < 2; ++tn) {
        const int row = wn + tn * 16 + fm;
        const int c8 = (s * 4 + quad) ^ (row & 7);
        bfr[tn] = *(const bf16x8*)&Bs[row * 64 + c8 * 8];
      }
#pragma unroll
      for (int tn = 0; tn < 2; ++tn)
        acc[tn] = __builtin_amdgcn_mfma_f32_16x16x32_bf16(af, bfr[tn], acc[tn], 0, 0, 0);
    }
    __syncthreads();
  }
#pragma unroll
  for (int tn = 0; tn < 2; ++tn) {
    const int col = n0 + wn + tn * 16 + fm;
#pragma unroll
    for (int r = 0; r < 4; ++r) {
      const int row = m0 + wm + quad * 4 + r;
      Cbf[(size_t)b * NN * DD + (size_t)row * DD + col] = f2bf(acc[tn][r]);
    }
  }
}

// -------- gate GEMM 32x64 tile + sigmoid/blend. final=0: Uout fp32 + Ubf_out + UT.
// final=1: writes out's update region + scatters into out's cand region. --------
__global__ __launch_bounds__(256) void gemm_gate_mfma(
    const ushort* __restrict__ Ubf, const ushort* __restrict__ Cbf,
    const ushort* __restrict__ WgT, const float* __restrict__ bg,
    const float* __restrict__ Uf, float* __restrict__ Uout,
    ushort* __restrict__ UbfOut, ushort* __restrict__ UTOut,
    const int* __restrict__ prune, const int* __restrict__ span_len,
    float* __restrict__ out_cand, int final_it) {
  __shared__ ushort As[32 * 64];
  __shared__ ushort Bs[64 * 64];
  __shared__ ushort Tt[32][66];
  const int b = blockIdx.z;
  const int m0 = blockIdx.y * 32, n0 = blockIdx.x * 64;
  const int tid = threadIdx.x;
  const int lane = tid & 63, wave = tid >> 6;
  const int wm = (wave >> 1) * 16, wn = (wave & 1) * 32;
  f32x4 acc[2] = {};
  const int fm = lane & 15, quad = lane >> 4;
  for (int k0 = 0; k0 < 2 * DD; k0 += 64) {
    const ushort* Abase = (k0 < DD) ? (Ubf + (size_t)b * NN * DD)
                                    : (Cbf + (size_t)b * NN * DD);
    const int kc = k0 & (DD - 1);
    {
      const int r = tid >> 3, c8 = tid & 7;
      const int g = c8 ^ (r & 7);
      GLDS(Abase + (size_t)(m0 + r) * DD + kc + g * 8, As + tid * 8);
    }
#pragma unroll
    for (int t = 0; t < 2; ++t) {
      const int idx = tid + t * 256;
      const int r = idx >> 3, c8 = idx & 7;
      const int g = c8 ^ (r & 7);
      GLDS(WgT + (size_t)(n0 + r) * (2 * DD) + k0 + g * 8, Bs + idx * 8);
    }
    __syncthreads();
#pragma unroll
    for (int s = 0; s < 2; ++s) {
      bf16x8 af, bfr[2];
      {
        const int row = wm + fm;
        const int c8 = (s * 4 + quad) ^ (row & 7);
        af = *(const bf16x8*)&As[row * 64 + c8 * 8];
      }
#pragma unroll
      for (int tn = 0; tn < 2; ++tn) {
        const int row = wn + tn * 16 + fm;
        const int c8 = (s * 4 + quad) ^ (row & 7);
        bfr[tn] = *(const bf16x8*)&Bs[row * 64 + c8 * 8];
      }
#pragma unroll
      for (int tn = 0; tn < 2; ++tn)
        acc[tn] = __builtin_amdgcn_mfma_f32_16x16x32_bf16(af, bfr[tn], acc[tn], 0, 0, 0);
    }
    __syncthreads();
  }
  const int slen = span_len[b];
#pragma unroll
  for (int tn = 0; tn < 2; ++tn) {
    const int cl = wn + tn * 16 + fm;
    const int col = n0 + cl;
    const float bgv = bg[col];
#pragma unroll
    for (int r = 0; r < 4; ++r) {
      const int rl = wm + quad * 4 + r;
      const int row = m0 + rl;
      const size_t off = (size_t)b * NN * DD + (size_t)row * DD + col;
      const float g = 1.f / (1.f + __expf(-(acc[tn][r] + bgv)));
      const float cv = __uint_as_float(((uint32_t)Cbf[off]) << 16);
      const float o = g * Uf[off] + (1.f - g) * cv;
      Uout[off] = o;
      if (final_it) {
        if (row < slen) {
          const int dst = prune[b * NN + row];
          out_cand[((size_t)b * MM + dst) * DD + col] = o;
        }
      } else {
        const ushort ob = f2bf(o);
        UbfOut[off] = ob;
        Tt[rl][cl] = ob;
      }
    }
  }
  if (!final_it) {
    __syncthreads();
#pragma unroll
    for (int p = 0; p < 2; ++p) {
      const int cl = (tid >> 3) + p * 32;     // 64 cols
      const int rl = (tid & 7) * 4;           // 32 rows
      ushort4 o;
      o.x = Tt[rl + 0][cl]; o.y = Tt[rl + 1][cl];
      o.z = Tt[rl + 2][cl]; o.w = Tt[rl + 3][cl];
      *(ushort4*)&UTOut[((size_t)b * DD + n0 + cl) * NN + m0 + rl] = o;
    }
  }
}

extern "C" void kernel_launch(void* const* d_in, const int* in_sizes, int n_in,
                              void* d_out, int out_size, void* d_ws, size_t ws_size,
                              hipStream_t stream) {
  const float* update = (const float*)d_in[0];
  const float* mask = (const float*)d_in[1];
  const float* cand = (const float*)d_in[2];
  const int* span_begin = (const int*)d_in[3];
  const int* prune = (const int*)d_in[5];
  const int* span_len = (const int*)d_in[6];
  const float* Wl = (const float*)d_in[7];
  const float* Wr = (const float*)d_in[8];
  const float* b_h = (const float*)d_in[9];
  const float* dist_emb = (const float*)d_in[10];
  const float* v_out = (const float*)d_in[11];
  const float* Wg = (const float*)d_in[13];
  const float* b_gate = (const float*)d_in[14];

  char* w = (char*)d_ws;
  float* left = (float*)w;        w += (size_t)NB * NN * HH * 4;   // 512 KB
  ushort* right_bf = (ushort*)w;  w += (size_t)NB * NN * HH * 2;   // 256 KB
  ushort* probs_bf = (ushort*)w;  w += (size_t)NB * NN * NN * 2;   // 4 MB
  ushort* ctxt_bf = (ushort*)w;   w += (size_t)NB * NN * DD * 2;   // 2 MB
  float* upd1 = (float*)w;        w += (size_t)NB * NN * DD * 4;   // 4 MB
  ushort* Ubf0 = (ushort*)w;      w += (size_t)NB * NN * DD * 2;   // 2 MB
  ushort* Ubf1 = (ushort*)w;      w += (size_t)NB * NN * DD * 2;   // 2 MB
  ushort* UT = (ushort*)w;        w += (size_t)NB * NN * DD * 2;   // 2 MB
  ushort* WgT = (ushort*)w;       w += (size_t)2 * DD * DD * 2;    // 1 MB

  float* out = (float*)d_out;
  float* out_upd = out + (size_t)NB * MM * DD;   // update output region

  prep_kernel<<<512, 256, 0, stream>>>(Wg, WgT, update, Ubf0, UT, cand, out,
                                       Wl, Wr, left, right_bf);
  // iteration 0
  score_softmax<<<dim3(NN / 4, NB), 256, 0, stream>>>(
      left, right_bf, span_begin, mask, dist_emb, b_h, v_out, probs_bf);
  gemm_ctxt_mfma<<<dim3(8, 32, NB), 256, 0, stream>>>(probs_bf, UT, ctxt_bf);
  gemm_gate_mfma<<<dim3(8, 32, NB), 256, 0, stream>>>(
      Ubf0, ctxt_bf, WgT, b_gate, update, upd1, Ubf1, UT,
      prune, span_len, out, 0);
  // iteration 1
  lr_kernel<<<512, 256, 0, stream>>>(upd1, Wl, Wr, left, right_bf);
  score_softmax<<<dim3(NN / 4, NB), 256, 0, stream>>>(
      left, right_bf, span_begin, mask, dist_emb, b_h, v_out, probs_bf);
  gemm_ctxt_mfma<<<dim3(8, 32, NB), 256, 0, stream>>>(probs_bf, UT, ctxt_bf);
  gemm_gate_mfma<<<dim3(8, 32, NB), 256, 0, stream>>>(
      Ubf1, ctxt_bf, WgT, b_gate, upd1, out_upd, nullptr, nullptr,
      prune, span_len, out, 1);
}

// Round 12
// 222.035 us; speedup vs baseline: 4.1155x; 1.0452x over previous
//
#include <hip/hip_runtime.h>
#include <cstdint>

#define NB 2
#define NN 1024
#define MM 2048
#define DD 512
#define HH 64
#define ST 68          // padded LDS stride (floats)
#define STB 72         // padded LDS stride (ushorts)

typedef __attribute__((ext_vector_type(8))) short bf16x8;
typedef __attribute__((ext_vector_type(4))) float f32x4;

__device__ inline ushort f2bf(float x) {
  union { float f; uint32_t u; } v; v.f = x;
  uint32_t u = v.u;
  u += 0x7FFF + ((u >> 16) & 1);      // RNE
  return (ushort)(u >> 16);
}
__device__ inline float bflo(uint32_t d) { return __uint_as_float(d << 16); }
__device__ inline float bfhi(uint32_t d) { return __uint_as_float(d & 0xFFFF0000u); }

#define GLDS(gp, lp) \
  __builtin_amdgcn_global_load_lds( \
      (const __attribute__((address_space(1))) void*)(gp), \
      (__attribute__((address_space(3))) void*)(lp), 16, 0, 0)

// ==== prep: WgT conv + update->(Ubf0,UT) conv + cand->out copy + lr0 ====
__global__ __launch_bounds__(256) void prep_kernel(
    const float* __restrict__ Wg, ushort* __restrict__ WgT,
    const float* __restrict__ update, ushort* __restrict__ Ubf0,
    ushort* __restrict__ UT, const float* __restrict__ cand,
    float* __restrict__ out, const float* __restrict__ Wl,
    const float* __restrict__ Wr, float* __restrict__ left,
    ushort* __restrict__ right_bf) {
  __shared__ __align__(16) char smem[16640];
  const int bid = blockIdx.x;
  const int tid = threadIdx.x;
  const int tx = tid & 15, ty = tid >> 4;

  if (bid < 384) {
    const float* in;
    ushort* out_row;
    ushort* out_T;
    int R, C, r0, c0;
    if (bid < 128) {
      in = Wg; out_row = nullptr; out_T = WgT;
      R = 2 * DD; C = DD; r0 = (bid >> 3) * 64; c0 = (bid & 7) * 64;
    } else {
      const int t = bid - 128, b = t >> 7, rem = t & 127;
      in = update + (size_t)b * NN * DD;
      out_row = Ubf0 + (size_t)b * NN * DD;
      out_T = UT + (size_t)b * DD * NN;
      R = NN; C = DD; r0 = (rem >> 3) * 64; c0 = (rem & 7) * 64;
    }
    float (*tile)[65] = (float(*)[65])smem;
#pragma unroll
    for (int p = 0; p < 4; ++p) {
      const int r = ty + p * 16;
      const float4 v = *(const float4*)&in[(size_t)(r0 + r) * C + c0 + tx * 4];
      tile[r][tx * 4 + 0] = v.x; tile[r][tx * 4 + 1] = v.y;
      tile[r][tx * 4 + 2] = v.z; tile[r][tx * 4 + 3] = v.w;
      if (out_row) {
        ushort4 o = make_ushort4(f2bf(v.x), f2bf(v.y), f2bf(v.z), f2bf(v.w));
        *(ushort4*)&out_row[(size_t)(r0 + r) * C + c0 + tx * 4] = o;
      }
    }
    __syncthreads();
#pragma unroll
    for (int p = 0; p < 4; ++p) {
      const int rr = ty + p * 16;
      ushort4 o;
      o.x = f2bf(tile[tx * 4 + 0][rr]);
      o.y = f2bf(tile[tx * 4 + 1][rr]);
      o.z = f2bf(tile[tx * 4 + 2][rr]);
      o.w = f2bf(tile[tx * 4 + 3][rr]);
      *(ushort4*)&out_T[(size_t)(c0 + rr) * R + r0 + tx * 4] = o;
    }
    __syncthreads();
  }

  // ---- lr0: 4 rows per block ----
  {
    float (*u)[DD] = (float(*)[DD])smem;
    const float4* Uv = (const float4*)(update + (size_t)bid * 4 * DD);
    float4* uv = (float4*)&u[0][0];
#pragma unroll
    for (int t = 0; t < 2; ++t) uv[tid + t * 256] = Uv[tid + t * 256];
    __syncthreads();
    const int h = tid & 63;
    const int isR = (tid >> 6) & 1;
    const int rsel = tid >> 7;
    const float* __restrict__ W = isR ? Wr : Wl;
    float acc[2] = {0.f, 0.f};
    for (int k0 = 0; k0 < DD; k0 += 4) {
      float w0 = W[(k0 + 0) * HH + h];
      float w1 = W[(k0 + 1) * HH + h];
      float w2 = W[(k0 + 2) * HH + h];
      float w3 = W[(k0 + 3) * HH + h];
#pragma unroll
      for (int r = 0; r < 2; ++r) {
        float4 u4 = *(const float4*)&u[rsel + r * 2][k0];
        acc[r] = fmaf(u4.w, w3, fmaf(u4.z, w2, fmaf(u4.y, w1, fmaf(u4.x, w0, acc[r]))));
      }
    }
    if (isR) {
#pragma unroll
      for (int r = 0; r < 2; ++r)
        right_bf[(size_t)(bid * 4 + rsel + r * 2) * HH + h] = f2bf(acc[r]);
    } else {
#pragma unroll
      for (int r = 0; r < 2; ++r)
        left[(size_t)(bid * 4 + rsel + r * 2) * HH + h] = acc[r];
    }
  }

  // ---- cand -> out head copy ----
  {
    const float4* c4 = (const float4*)cand;
    float4* o4 = (float4*)out;
    for (int idx = bid * 256 + tid; idx < NB * MM * DD / 4; idx += 512 * 256)
      o4[idx] = c4[idx];
  }
}

// ---- standalone lr (iteration 1) ----
__global__ __launch_bounds__(256) void lr_kernel(
    const float* __restrict__ U, const float* __restrict__ Wl,
    const float* __restrict__ Wr, float* __restrict__ left,
    ushort* __restrict__ right_bf) {
  __shared__ float u[4][DD];
  const int bid = blockIdx.x;
  const int tid = threadIdx.x;
  const float4* Uv = (const float4*)(U + (size_t)bid * 4 * DD);
  float4* uv = (float4*)&u[0][0];
#pragma unroll
  for (int t = 0; t < 2; ++t) uv[tid + t * 256] = Uv[tid + t * 256];
  __syncthreads();
  const int h = tid & 63;
  const int isR = (tid >> 6) & 1;
  const int rsel = tid >> 7;
  const float* __restrict__ W = isR ? Wr : Wl;
  float acc[2] = {0.f, 0.f};
  for (int k0 = 0; k0 < DD; k0 += 4) {
    float w0 = W[(k0 + 0) * HH + h];
    float w1 = W[(k0 + 1) * HH + h];
    float w2 = W[(k0 + 2) * HH + h];
    float w3 = W[(k0 + 3) * HH + h];
#pragma unroll
    for (int r = 0; r < 2; ++r) {
      float4 u4 = *(const float4*)&u[rsel + r * 2][k0];
      acc[r] = fmaf(u4.w, w3, fmaf(u4.z, w2, fmaf(u4.y, w1, fmaf(u4.x, w0, acc[r]))));
    }
  }
  if (isR) {
#pragma unroll
    for (int r = 0; r < 2; ++r)
      right_bf[(size_t)(bid * 4 + rsel + r * 2) * HH + h] = f2bf(acc[r]);
  } else {
#pragma unroll
    for (int r = 0; r < 2; ++r)
      left[(size_t)(bid * 4 + rsel + r * 2) * HH + h] = acc[r];
  }
}

// ---- fused score + softmax -> bf16 probs. 4 rows/block, j-chunks of 128 ----
__global__ __launch_bounds__(256) void score_softmax(
    const float* __restrict__ left, const ushort* __restrict__ right_bf,
    const int* __restrict__ span_begin, const float* __restrict__ mask,
    const float* __restrict__ dist_emb, const float* __restrict__ b_h,
    const float* __restrict__ v_out, ushort* __restrict__ probs_bf) {
  __shared__ ushort Rt[128][STB];
  __shared__ ushort LDb[4][10][STB];
  __shared__ float Dbh[10][ST];
  __shared__ float Lt[4][ST];
  __shared__ float Sc[4][NN];
  __shared__ int sbj[NN];
  const int b = blockIdx.y;
  const int r0 = blockIdx.x * 4;
  const int tid = threadIdx.x;
  const int wave = tid >> 6, lane = tid & 63;
  const int row = r0 + wave;

  for (int f = tid; f < 160; f += 256) {
    int bk = f >> 4, h4 = f & 15;
    float4 d = *(const float4*)&dist_emb[bk * HH + h4 * 4];
    float4 bh = *(const float4*)&b_h[h4 * 4];
    d.x += bh.x; d.y += bh.y; d.z += bh.z; d.w += bh.w;
    *(float4*)&Dbh[bk][h4 * 4] = d;
  }
  if (tid < 64) {
    int r = tid >> 4, h4 = tid & 15;
    *(float4*)&Lt[r][h4 * 4] =
        *(const float4*)&left[((size_t)b * NN + r0 + r) * HH + h4 * 4];
  }
  for (int t = tid; t < NN; t += 256) sbj[t] = span_begin[b * NN + t];
  __syncthreads();
  for (int f = tid; f < 2560; f += 256) {
    int i = f / 640;
    int rem = f - i * 640;
    int bk = rem >> 6, h = rem & 63;
    LDb[i][bk][h] = f2bf(Lt[i][h] + Dbh[bk][h]);
  }
  float4 vr[16];
#pragma unroll
  for (int hq = 0; hq < 16; ++hq) vr[hq] = *(const float4*)&v_out[hq * 4];
  const int my_sbi = span_begin[(size_t)b * NN + row];
  const float* maskrow = mask + ((size_t)b * NN + row) * NN;

#pragma unroll 1
  for (int c = 0; c < 8; ++c) {
    __syncthreads();
#pragma unroll
    for (int t = 0; t < 4; ++t) {
      const int f = tid + t * 256;
      const int r = f >> 3, u8 = f & 7;
      *(bf16x8*)&Rt[r][u8 * 8] =
          *(const bf16x8*)&right_bf[((size_t)b * NN + c * 128 + r) * HH + u8 * 8];
    }
    __syncthreads();
#pragma unroll 1
    for (int half = 0; half < 2; ++half) {
      const int j = c * 128 + half * 64 + lane;
      int d = sbj[j] - my_sbi;
      d = d < 0 ? -d : d;
      const int bk =
          d <= 4 ? d : (d <= 7 ? 5 : (d <= 15 ? 6 : (d <= 31 ? 7 : (d <= 63 ? 8 : 9))));
      const ushort* zp = &LDb[wave][bk][0];
      const ushort* rp = &Rt[half * 64 + lane][0];
      float acc0 = 0.f, acc1 = 0.f;
#pragma unroll
      for (int oct = 0; oct < 8; oct += 2) {
        {
          const uint4 zd = *(const uint4*)&zp[oct * 8];
          const uint4 rd = *(const uint4*)&rp[oct * 8];
          const float4 v0 = vr[2 * oct], v1 = vr[2 * oct + 1];
          acc0 = fmaf(fmaxf(bflo(zd.x) + bflo(rd.x), 0.f), v0.x, acc0);
          acc0 = fmaf(fmaxf(bfhi(zd.x) + bfhi(rd.x), 0.f), v0.y, acc0);
          acc0 = fmaf(fmaxf(bflo(zd.y) + bflo(rd.y), 0.f), v0.z, acc0);
          acc0 = fmaf(fmaxf(bfhi(zd.y) + bfhi(rd.y), 0.f), v0.w, acc0);
          acc0 = fmaf(fmaxf(bflo(zd.z) + bflo(rd.z), 0.f), v1.x, acc0);
          acc0 = fmaf(fmaxf(bfhi(zd.z) + bfhi(rd.z), 0.f), v1.y, acc0);
          acc0 = fmaf(fmaxf(bflo(zd.w) + bflo(rd.w), 0.f), v1.z, acc0);
          acc0 = fmaf(fmaxf(bfhi(zd.w) + bfhi(rd.w), 0.f), v1.w, acc0);
        }
        {
          const uint4 zd = *(const uint4*)&zp[(oct + 1) * 8];
          const uint4 rd = *(const uint4*)&rp[(oct + 1) * 8];
          const float4 v0 = vr[2 * oct + 2], v1 = vr[2 * oct + 3];
          acc1 = fmaf(fmaxf(bflo(zd.x) + bflo(rd.x), 0.f), v0.x, acc1);
          acc1 = fmaf(fmaxf(bfhi(zd.x) + bfhi(rd.x), 0.f), v0.y, acc1);
          acc1 = fmaf(fmaxf(bflo(zd.y) + bflo(rd.y), 0.f), v0.z, acc1);
          acc1 = fmaf(fmaxf(bfhi(zd.y) + bfhi(rd.y), 0.f), v0.w, acc1);
          acc1 = fmaf(fmaxf(bflo(zd.z) + bflo(rd.z), 0.f), v1.x, acc1);
          acc1 = fmaf(fmaxf(bfhi(zd.z) + bfhi(rd.z), 0.f), v1.y, acc1);
          acc1 = fmaf(fmaxf(bflo(zd.w) + bflo(rd.w), 0.f), v1.z, acc1);
          acc1 = fmaf(fmaxf(bfhi(zd.w) + bfhi(rd.w), 0.f), v1.w, acc1);
        }
      }
      const float mval = maskrow[j];
      Sc[wave][j] = (acc0 + acc1) - (1.0f - mval) * 1e23f;
    }
  }
  float mx = -3.0e38f;
#pragma unroll
  for (int c = 0; c < 16; ++c) mx = fmaxf(mx, Sc[wave][c * 64 + lane]);
#pragma unroll
  for (int off = 32; off; off >>= 1) mx = fmaxf(mx, __shfl_xor(mx, off));
  float sum = 0.f;
#pragma unroll
  for (int c = 0; c < 16; ++c) {
    const float e = __expf(Sc[wave][c * 64 + lane] - mx);
    Sc[wave][c * 64 + lane] = e;
    sum += e;
  }
#pragma unroll
  for (int off = 32; off; off >>= 1) sum += __shfl_xor(sum, off);
  const float inv = 1.0f / sum;
  ushort* prow = probs_bf + ((size_t)b * NN + row) * NN;
#pragma unroll
  for (int c = 0; c < 16; ++c)
    prow[c * 64 + lane] = f2bf(Sc[wave][c * 64 + lane] * inv);
}

// -------- ctxt(bf16) = P @ U, bf16 MFMA, 32x64 tile, BK=128 (8 K-iters) --------
__global__ __launch_bounds__(256) void gemm_ctxt_mfma(
    const ushort* __restrict__ Pbf, const ushort* __restrict__ UT,
    ushort* __restrict__ Cbf) {
  __shared__ ushort As[32 * 128];      // 8 KB
  __shared__ ushort Bs[64 * 128];      // 16 KB
  const int b = blockIdx.z;
  const int m0 = blockIdx.y * 32, n0 = blockIdx.x * 64;
  const int tid = threadIdx.x;
  const int lane = tid & 63, wave = tid >> 6;
  const int wm = (wave >> 1) * 16, wn = (wave & 1) * 32;
  const ushort* Ab = Pbf + (size_t)b * NN * NN;
  const ushort* Bb = UT + (size_t)b * DD * NN;
  f32x4 acc[2] = {};
  const int fm = lane & 15, quad = lane >> 4;
  for (int k0 = 0; k0 < NN; k0 += 128) {
#pragma unroll
    for (int t = 0; t < 2; ++t) {  // A: 32 rows x 16 chunks = 512 GLDS
      const int idx = tid + t * 256;
      const int r = idx >> 4, c16 = idx & 15;
      const int g = c16 ^ (r & 15);
      GLDS(Ab + (size_t)(m0 + r) * NN + k0 + g * 8, As + idx * 8);
    }
#pragma unroll
    for (int t = 0; t < 4; ++t) {  // B: 64 rows x 16 chunks = 1024 GLDS
      const int idx = tid + t * 256;
      const int r = idx >> 4, c16 = idx & 15;
      const int g = c16 ^ (r & 15);
      GLDS(Bb + (size_t)(n0 + r) * NN + k0 + g * 8, Bs + idx * 8);
    }
    __syncthreads();
#pragma unroll
    for (int s = 0; s < 4; ++s) {
      bf16x8 af, bfr[2];
      {
        const int row = wm + fm;
        const int c16 = (s * 4 + quad) ^ (row & 15);
        af = *(const bf16x8*)&As[row * 128 + c16 * 8];
      }
#pragma unroll
      for (int tn = 0; tn < 2; ++tn) {
        const int row = wn + tn * 16 + fm;
        const int c16 = (s * 4 + quad) ^ (row & 15);
        bfr[tn] = *(const bf16x8*)&Bs[row * 128 + c16 * 8];
      }
#pragma unroll
      for (int tn = 0; tn < 2; ++tn)
        acc[tn] = __builtin_amdgcn_mfma_f32_16x16x32_bf16(af, bfr[tn], acc[tn], 0, 0, 0);
    }
    __syncthreads();
  }
#pragma unroll
  for (int tn = 0; tn < 2; ++tn) {
    const int col = n0 + wn + tn * 16 + fm;
#pragma unroll
    for (int r = 0; r < 4; ++r) {
      const int row = m0 + wm + quad * 4 + r;
      Cbf[(size_t)b * NN * DD + (size_t)row * DD + col] = f2bf(acc[tn][r]);
    }
  }
}

// -------- gate GEMM 32x64 tile, BK=128 + sigmoid/blend epilogue --------
__global__ __launch_bounds__(256) void gemm_gate_mfma(
    const ushort* __restrict__ Ubf, const ushort* __restrict__ Cbf,
    const ushort* __restrict__ WgT, const float* __restrict__ bg,
    const float* __restrict__ Uf, float* __restrict__ Uout,
    ushort* __restrict__ UbfOut, ushort* __restrict__ UTOut,
    const int* __restrict__ prune, const int* __restrict__ span_len,
    float* __restrict__ out_cand, int final_it) {
  __shared__ ushort As[32 * 128];
  __shared__ ushort Bs[64 * 128];
  __shared__ ushort Tt[32][66];
  const int b = blockIdx.z;
  const int m0 = blockIdx.y * 32, n0 = blockIdx.x * 64;
  const int tid = threadIdx.x;
  const int lane = tid & 63, wave = tid >> 6;
  const int wm = (wave >> 1) * 16, wn = (wave & 1) * 32;
  f32x4 acc[2] = {};
  const int fm = lane & 15, quad = lane >> 4;
  for (int k0 = 0; k0 < 2 * DD; k0 += 128) {
    const ushort* Abase = (k0 < DD) ? (Ubf + (size_t)b * NN * DD)
                                    : (Cbf + (size_t)b * NN * DD);
    const int kc = k0 & (DD - 1);
#pragma unroll
    for (int t = 0; t < 2; ++t) {
      const int idx = tid + t * 256;
      const int r = idx >> 4, c16 = idx & 15;
      const int g = c16 ^ (r & 15);
      GLDS(Abase + (size_t)(m0 + r) * DD + kc + g * 8, As + idx * 8);
    }
#pragma unroll
    for (int t = 0; t < 4; ++t) {
      const int idx = tid + t * 256;
      const int r = idx >> 4, c16 = idx & 15;
      const int g = c16 ^ (r & 15);
      GLDS(WgT + (size_t)(n0 + r) * (2 * DD) + k0 + g * 8, Bs + idx * 8);
    }
    __syncthreads();
#pragma unroll
    for (int s = 0; s < 4; ++s) {
      bf16x8 af, bfr[2];
      {
        const int row = wm + fm;
        const int c16 = (s * 4 + quad) ^ (row & 15);
        af = *(const bf16x8*)&As[row * 128 + c16 * 8];
      }
#pragma unroll
      for (int tn = 0; tn < 2; ++tn) {
        const int row = wn + tn * 16 + fm;
        const int c16 = (s * 4 + quad) ^ (row & 15);
        bfr[tn] = *(const bf16x8*)&Bs[row * 128 + c16 * 8];
      }
#pragma unroll
      for (int tn = 0; tn < 2; ++tn)
        acc[tn] = __builtin_amdgcn_mfma_f32_16x16x32_bf16(af, bfr[tn], acc[tn], 0, 0, 0);
    }
    __syncthreads();
  }
  const int slen = span_len[b];
#pragma unroll
  for (int tn = 0; tn < 2; ++tn) {
    const int cl = wn + tn * 16 + fm;
    const int col = n0 + cl;
    const float bgv = bg[col];
#pragma unroll
    for (int r = 0; r < 4; ++r) {
      const int rl = wm + quad * 4 + r;
      const int row = m0 + rl;
      const size_t off = (size_t)b * NN * DD + (size_t)row * DD + col;
      const float g = 1.f / (1.f + __expf(-(acc[tn][r] + bgv)));
      const float cv = __uint_as_float(((uint32_t)Cbf[off]) << 16);
      const float o = g * Uf[off] + (1.f - g) * cv;
      Uout[off] = o;
      if (final_it) {
        if (row < slen) {
          const int dst = prune[b * NN + row];
          out_cand[((size_t)b * MM + dst) * DD + col] = o;
        }
      } else {
        const ushort ob = f2bf(o);
        UbfOut[off] = ob;
        Tt[rl][cl] = ob;
      }
    }
  }
  if (!final_it) {
    __syncthreads();
#pragma unroll
    for (int p = 0; p < 2; ++p) {
      const int cl = (tid >> 3) + p * 32;
      const int rl = (tid & 7) * 4;
      ushort4 o;
      o.x = Tt[rl + 0][cl]; o.y = Tt[rl + 1][cl];
      o.z = Tt[rl + 2][cl]; o.w = Tt[rl + 3][cl];
      *(ushort4*)&UTOut[((size_t)b * DD + n0 + cl) * NN + m0 + rl] = o;
    }
  }
}

extern "C" void kernel_launch(void* const* d_in, const int* in_sizes, int n_in,
                              void* d_out, int out_size, void* d_ws, size_t ws_size,
                              hipStream_t stream) {
  const float* update = (const float*)d_in[0];
  const float* mask = (const float*)d_in[1];
  const float* cand = (const float*)d_in[2];
  const int* span_begin = (const int*)d_in[3];
  const int* prune = (const int*)d_in[5];
  const int* span_len = (const int*)d_in[6];
  const float* Wl = (const float*)d_in[7];
  const float* Wr = (const float*)d_in[8];
  const float* b_h = (const float*)d_in[9];
  const float* dist_emb = (const float*)d_in[10];
  const float* v_out = (const float*)d_in[11];
  const float* Wg = (const float*)d_in[13];
  const float* b_gate = (const float*)d_in[14];

  char* w = (char*)d_ws;
  float* left = (float*)w;        w += (size_t)NB * NN * HH * 4;   // 512 KB
  ushort* right_bf = (ushort*)w;  w += (size_t)NB * NN * HH * 2;   // 256 KB
  ushort* probs_bf = (ushort*)w;  w += (size_t)NB * NN * NN * 2;   // 4 MB
  ushort* ctxt_bf = (ushort*)w;   w += (size_t)NB * NN * DD * 2;   // 2 MB
  float* upd1 = (float*)w;        w += (size_t)NB * NN * DD * 4;   // 4 MB
  ushort* Ubf0 = (ushort*)w;      w += (size_t)NB * NN * DD * 2;   // 2 MB
  ushort* Ubf1 = (ushort*)w;      w += (size_t)NB * NN * DD * 2;   // 2 MB
  ushort* UT = (ushort*)w;        w += (size_t)NB * NN * DD * 2;   // 2 MB
  ushort* WgT = (ushort*)w;       w += (size_t)2 * DD * DD * 2;    // 1 MB

  float* out = (float*)d_out;
  float* out_upd = out + (size_t)NB * MM * DD;

  prep_kernel<<<512, 256, 0, stream>>>(Wg, WgT, update, Ubf0, UT, cand, out,
                                       Wl, Wr, left, right_bf);
  // iteration 0
  score_softmax<<<dim3(NN / 4, NB), 256, 0, stream>>>(
      left, right_bf, span_begin, mask, dist_emb, b_h, v_out, probs_bf);
  gemm_ctxt_mfma<<<dim3(8, 32, NB), 256, 0, stream>>>(probs_bf, UT, ctxt_bf);
  gemm_gate_mfma<<<dim3(8, 32, NB), 256, 0, stream>>>(
      Ubf0, ctxt_bf, WgT, b_gate, update, upd1, Ubf1, UT,
      prune, span_len, out, 0);
  // iteration 1
  lr_kernel<<<512, 256, 0, stream>>>(upd1, Wl, Wr, left, right_bf);
  score_softmax<<<dim3(NN / 4, NB), 256, 0, stream>>>(
      left, right_bf, span_begin, mask, dist_emb, b_h, v_out, probs_bf);
  gemm_ctxt_mfma<<<dim3(8, 32, NB), 256, 0, stream>>>(probs_bf, UT, ctxt_bf);
  gemm_gate_mfma<<<dim3(8, 32, NB), 256, 0, stream>>>(
      Ubf1, ctxt_bf, WgT, b_gate, upd1, out_upd, nullptr, nullptr,
      prune, span_len, out, 1);
}